// Round 3
// baseline (338.342 us; speedup 1.0000x reference)
//
#include <hip/hip_runtime.h>
#include <hip/hip_bf16.h>

// ---------------------------------------------------------------------------
// Problem: N=2, S=2048, C=1024, A=1024, H=16, d=64, MAXLEN=2048
// Outputs: y [2,2048,1024] fp32  then  attn [2,16,2048,2048] fp32 (concat flat)
// ---------------------------------------------------------------------------

typedef __attribute__((ext_vector_type(8))) short s16x8;   // 8 x bf16 bits (4 VGPR)
typedef __attribute__((ext_vector_type(4))) float f32x4;   // MFMA acc

#define NEGV (-1e30f)
#define K1   0.1803368801111244f   /* 0.125 * log2(e) */

static __device__ __forceinline__ short f2bf(float f) {
  unsigned u = __float_as_uint(f);
  unsigned r = (u + 0x7fffu + ((u >> 16) & 1u)) >> 16;
  return (short)r;
}
static __device__ __forceinline__ float bf2f(short s) {
  return __uint_as_float(((unsigned)(unsigned short)s) << 16);
}

// ---------------- elementwise cast fp32 -> bf16 ----------------------------
__global__ void cast_f32_bf16(const float* __restrict__ in, short* __restrict__ out, int n) {
  int i = (blockIdx.x * 256 + threadIdx.x) * 8;
  if (i >= n) return;
  float4 a = *(const float4*)&in[i];
  float4 b = *(const float4*)&in[i + 4];
  s16x8 v;
  v[0] = f2bf(a.x); v[1] = f2bf(a.y); v[2] = f2bf(a.z); v[3] = f2bf(a.w);
  v[4] = f2bf(b.x); v[5] = f2bf(b.y); v[6] = f2bf(b.z); v[7] = f2bf(b.w);
  *(s16x8*)&out[i] = v;
}

// ---------------- transpose + cast: [R][Cc] fp32 -> [Cc][R] bf16 -----------
__global__ void transpose_cast(const float* __restrict__ in, short* __restrict__ out,
                               int R, int Cc) {
  __shared__ float tile[32][33];
  int c0 = blockIdx.x * 32, r0 = blockIdx.y * 32;
  int tx = threadIdx.x, ty = threadIdx.y;          // block (32,8)
  for (int i = 0; i < 32; i += 8)
    tile[ty + i][tx] = in[(size_t)(r0 + ty + i) * Cc + c0 + tx];
  __syncthreads();
  for (int i = 0; i < 32; i += 8)
    out[(size_t)(c0 + ty + i) * R + r0 + tx] = f2bf(tile[tx][ty + i]);
}

// -------- rel_table [2048][16] fp32 -> [16][2048] bf16, scaled by log2e ----
__global__ void transpose_table_k(const float* __restrict__ in, short* __restrict__ out) {
  int i = blockIdx.x * 256 + threadIdx.x;
  if (i >= 2048 * 16) return;
  int l = i >> 4, h = i & 15;
  out[h * 2048 + l] = f2bf(in[i] * 1.4426950408889634f);
}

// ---------------- V pre-transpose: qkv V-part -> VT[n][vcol][s] bf16 -------
__global__ void vt_transpose(const short* __restrict__ qkv, short* __restrict__ vt) {
  __shared__ short tile[32][33];
  int nn = blockIdx.z;
  int c0 = blockIdx.y * 32;                        // v-col 0..1023 (= h*64+dd)
  int r0 = blockIdx.x * 32;                        // s
  int tx = threadIdx.x, ty = threadIdx.y;          // block (32,8)
  for (int i = 0; i < 32; i += 8)
    tile[ty + i][tx] = qkv[(size_t)(nn * 2048 + r0 + ty + i) * 3072 + 2048 + c0 + tx];
  __syncthreads();
  for (int i = 0; i < 32; i += 8)
    vt[(size_t)(nn * 1024 + c0 + ty + i) * 2048 + r0 + tx] = tile[tx][ty + i];
}

// ---------------- bf16 MFMA GEMM: C = A[M][K] * BT[Nn][K]^T ----------------
template<bool OUT_F32>
__global__ __launch_bounds__(256) void gemm_bt(
    const short* __restrict__ A, const short* __restrict__ BT,
    void* __restrict__ Cout, int M, int Nn, int K)
{
  __shared__ short As[128][72];
  __shared__ short Bs[128][72];
  int bn = blockIdx.x, bm = blockIdx.y;
  int tid = threadIdx.x, wave = tid >> 6, lane = tid & 63;
  int wr = wave >> 1, wc = wave & 1;
  int lc = lane & 15, lg = lane >> 4;
  f32x4 acc[4][4];
  for (int i = 0; i < 4; ++i)
    for (int j = 0; j < 4; ++j) acc[i][j] = (f32x4){0.f, 0.f, 0.f, 0.f};
  const short* Abase = A  + (size_t)(bm * 128) * K;
  const short* Bbase = BT + (size_t)(bn * 128) * K;
  for (int k0 = 0; k0 < K; k0 += 64) {
    __syncthreads();
    for (int it = 0; it < 4; ++it) {
      int lid = tid + it * 256;
      int r = lid >> 3, ck = (lid & 7) * 8;
      *(s16x8*)&As[r][ck] = *(const s16x8*)&Abase[(size_t)r * K + k0 + ck];
      *(s16x8*)&Bs[r][ck] = *(const s16x8*)&Bbase[(size_t)r * K + k0 + ck];
    }
    __syncthreads();
    for (int ks = 0; ks < 2; ++ks) {
      s16x8 af[4], bfr[4];
      for (int mi = 0; mi < 4; ++mi)
        af[mi] = *(const s16x8*)&As[wr * 64 + mi * 16 + lc][ks * 32 + lg * 8];
      for (int ni = 0; ni < 4; ++ni)
        bfr[ni] = *(const s16x8*)&Bs[wc * 64 + ni * 16 + lc][ks * 32 + lg * 8];
      for (int mi = 0; mi < 4; ++mi)
        for (int ni = 0; ni < 4; ++ni)
          acc[mi][ni] = __builtin_amdgcn_mfma_f32_16x16x32_bf16(af[mi], bfr[ni], acc[mi][ni], 0, 0, 0);
    }
  }
  int row0 = bm * 128 + wr * 64, col0 = bn * 128 + wc * 64;
  for (int mi = 0; mi < 4; ++mi)
    for (int ni = 0; ni < 4; ++ni)
      for (int r = 0; r < 4; ++r) {
        int row = row0 + mi * 16 + lg * 4 + r;
        int col = col0 + ni * 16 + lc;
        if constexpr (OUT_F32)
          ((float*)Cout)[(size_t)row * Nn + col] = acc[mi][ni][r];
        else
          ((short*)Cout)[(size_t)row * Nn + col] = f2bf(acc[mi][ni][r]);
      }
}

// ---------------- attention pass 1: per-row (max, sum) stats ---------------
// grid 1024, desc-qt (LPT): bid -> qt = 31-(bid>>5), nh = bid&31 (bid%8=nh%8
// keeps XCD affinity). Swapped QK^T: lane owns q-row (lc), 4 k per acc reg.
// Log2-domain softmax: logits pre-scaled by log2e, exp2f = native v_exp.
// Double-buffered K LDS + reg prefetch: ONE barrier per k-tile.
__global__ __launch_bounds__(256) void attn_stats(
    const short* __restrict__ qkv,     // [4096][3072] bf16
    const int*   __restrict__ mask,    // [2][2048]
    const short* __restrict__ tabS,    // [16][2048] bf16, *log2e
    float2*      __restrict__ ml)      // [2][16][2048] (m_log2, l)
{
  int bid = blockIdx.x;
  int qt = 31 - (bid >> 5);
  int nh = bid & 31;
  int n = nh >> 4, h = nh & 15;
  int tid = threadIdx.x, wave = tid >> 6, lane = tid & 63;
  int lc = lane & 15, lg = lane >> 4;

  __shared__ short Qs[64][72];
  __shared__ short Ks[2][64][72];
  __shared__ short btab[2048];
  __shared__ unsigned char mk[2048];

  for (int i = tid; i < 2048; i += 256) {
    btab[i] = tabS[h * 2048 + i];
    mk[i] = (unsigned char)(mask[n * 2048 + i] != 0);
  }

  int sr = tid >> 3, sc = (tid & 7) * 8;           // staging coords (rows sr, sr+32)
  size_t rowbase = (size_t)(n * 2048 + qt * 64);
  const short* qbase = qkv + rowbase * 3072 + h * 64;
  const short* kb0 = qkv + (size_t)(n * 2048) * 3072 + 1024 + h * 64;
  *(s16x8*)&Qs[sr][sc]         = *(const s16x8*)&qbase[(size_t)sr * 3072 + sc];
  *(s16x8*)&Qs[sr + 32][sc]    = *(const s16x8*)&qbase[(size_t)(sr + 32) * 3072 + sc];
  *(s16x8*)&Ks[0][sr][sc]      = *(const s16x8*)&kb0[(size_t)sr * 3072 + sc];
  *(s16x8*)&Ks[0][sr + 32][sc] = *(const s16x8*)&kb0[(size_t)(sr + 32) * 3072 + sc];
  __syncthreads();

  s16x8 aq[2];
  #pragma unroll
  for (int ks = 0; ks < 2; ++ks)
    aq[ks] = *(const s16x8*)&Qs[wave * 16 + lc][ks * 32 + lg * 8];
  int qrow = qt * 64 + wave * 16 + lc;
  float m = NEGV, l = 0.f;

  for (int kt = 0; kt <= qt; ++kt) {
    int cur = kt & 1;
    s16x8 kn0, kn1;
    if (kt < qt) {                                 // prefetch next K tile -> regs
      const short* kb = qkv + (size_t)(n * 2048 + (kt + 1) * 64) * 3072 + 1024 + h * 64;
      kn0 = *(const s16x8*)&kb[(size_t)sr * 3072 + sc];
      kn1 = *(const s16x8*)&kb[(size_t)(sr + 32) * 3072 + sc];
    }
    f32x4 c[4];
    #pragma unroll
    for (int ni = 0; ni < 4; ++ni) {
      c[ni] = (f32x4){0.f, 0.f, 0.f, 0.f};
      #pragma unroll
      for (int ks = 0; ks < 2; ++ks) {
        s16x8 kf = *(const s16x8*)&Ks[cur][ni * 16 + lc][ks * 32 + lg * 8];
        c[ni] = __builtin_amdgcn_mfma_f32_16x16x32_bf16(kf, aq[ks], c[ni], 0, 0, 0);
      }
    }
    float vals[4][4], tmax = NEGV;
    #pragma unroll
    for (int ni = 0; ni < 4; ++ni)
      #pragma unroll
      for (int r = 0; r < 4; ++r) {
        int col = kt * 64 + ni * 16 + lg * 4 + r;
        bool ok = (col <= qrow) && mk[col];
        float v = ok ? fmaf(c[ni][r], K1, bf2f(btab[qrow - col])) : NEGV;
        vals[ni][r] = v;
        tmax = fmaxf(tmax, v);
      }
    tmax = fmaxf(tmax, __shfl_xor(tmax, 16));
    tmax = fmaxf(tmax, __shfl_xor(tmax, 32));
    float mn = fmaxf(m, tmax);
    float s = 0.f;
    #pragma unroll
    for (int ni = 0; ni < 4; ++ni)
      #pragma unroll
      for (int r = 0; r < 4; ++r)
        s += exp2f(vals[ni][r] - mn);
    s += __shfl_xor(s, 16);
    s += __shfl_xor(s, 32);
    l = l * exp2f(m - mn) + s;
    m = mn;
    if (kt < qt) {                                 // write prefetch -> other buffer
      *(s16x8*)&Ks[cur ^ 1][sr][sc] = kn0;
      *(s16x8*)&Ks[cur ^ 1][sr + 32][sc] = kn1;
    }
    __syncthreads();
  }
  if (lg == 0) {
    float2 v; v.x = m; v.y = l;
    ml[(size_t)(n * 16 + h) * 2048 + qrow] = v;
  }
}

// ---------------- attention pass 2: emit attn + PV -------------------------
// Same grid/mapping. QPs holds Q (pre-loop) then P tiles (wave-local strips:
// no barrier needed between P write and PV read). K/VT double-buffered with
// reg prefetch: ONE barrier per k-tile.
__global__ __launch_bounds__(256) void attn_emit(
    const short* __restrict__ qkv,     // [4096][3072] bf16
    const short* __restrict__ vt,      // [2][1024][2048] bf16 (V^T)
    const int*   __restrict__ mask,
    const short* __restrict__ tabS,
    const float2* __restrict__ ml,
    float* __restrict__ attn_out,      // [2][16][2048][2048]
    short* __restrict__ y_ws)          // [4096][1024] bf16
{
  int bid = blockIdx.x;
  int qt = 31 - (bid >> 5);
  int nh = bid & 31;
  int n = nh >> 4, h = nh & 15;
  int tid = threadIdx.x, wave = tid >> 6, lane = tid & 63;
  int lc = lane & 15, lg = lane >> 4;

  __shared__ short QPs[64][72];        // Q, then P (wave-local reuse)
  __shared__ short Ks[2][64][72];
  __shared__ short VTs[2][64][72];
  __shared__ short btab[2048];
  __shared__ unsigned char mk[2048];

  for (int i = tid; i < 2048; i += 256) {
    btab[i] = tabS[h * 2048 + i];
    mk[i] = (unsigned char)(mask[n * 2048 + i] != 0);
  }

  int sr = tid >> 3, sc = (tid & 7) * 8;
  size_t rowbase = (size_t)(n * 2048 + qt * 64);
  const short* qbase = qkv + rowbase * 3072 + h * 64;
  const short* kb0 = qkv + (size_t)(n * 2048) * 3072 + 1024 + h * 64;
  const short* vtbase = vt + (size_t)(n * 1024 + h * 64) * 2048;
  *(s16x8*)&QPs[sr][sc]         = *(const s16x8*)&qbase[(size_t)sr * 3072 + sc];
  *(s16x8*)&QPs[sr + 32][sc]    = *(const s16x8*)&qbase[(size_t)(sr + 32) * 3072 + sc];
  *(s16x8*)&Ks[0][sr][sc]       = *(const s16x8*)&kb0[(size_t)sr * 3072 + sc];
  *(s16x8*)&Ks[0][sr + 32][sc]  = *(const s16x8*)&kb0[(size_t)(sr + 32) * 3072 + sc];
  *(s16x8*)&VTs[0][sr][sc]      = *(const s16x8*)&vtbase[(size_t)sr * 2048 + sc];
  *(s16x8*)&VTs[0][sr + 32][sc] = *(const s16x8*)&vtbase[(size_t)(sr + 32) * 2048 + sc];
  __syncthreads();

  s16x8 aq[2];
  #pragma unroll
  for (int ks = 0; ks < 2; ++ks)
    aq[ks] = *(const s16x8*)&QPs[wave * 16 + lc][ks * 32 + lg * 8];
  int qrow = qt * 64 + wave * 16 + lc;

  float2 mlv = ml[(size_t)(n * 16 + h) * 2048 + qrow];
  float C = mlv.x + __log2f(mlv.y);    // p = exp2(valS - C); l >= 1 always
  bool qv = (mk[qrow] != 0);

  f32x4 yacc[4];
  #pragma unroll
  for (int ni = 0; ni < 4; ++ni) yacc[ni] = (f32x4){0.f, 0.f, 0.f, 0.f};

  float* aout = attn_out + (size_t)(n * 16 + h) * 2048 * 2048;

  for (int kt = 0; kt <= qt; ++kt) {
    int cur = kt & 1;
    s16x8 kn0, kn1, vn0, vn1;
    if (kt < qt) {                                 // prefetch next K,VT -> regs
      const short* kb = qkv + (size_t)(n * 2048 + (kt + 1) * 64) * 3072 + 1024 + h * 64;
      kn0 = *(const s16x8*)&kb[(size_t)sr * 3072 + sc];
      kn1 = *(const s16x8*)&kb[(size_t)(sr + 32) * 3072 + sc];
      vn0 = *(const s16x8*)&vtbase[(size_t)sr * 2048 + (kt + 1) * 64 + sc];
      vn1 = *(const s16x8*)&vtbase[(size_t)(sr + 32) * 2048 + (kt + 1) * 64 + sc];
    }
    f32x4 c[4];
    #pragma unroll
    for (int ni = 0; ni < 4; ++ni) {
      c[ni] = (f32x4){0.f, 0.f, 0.f, 0.f};
      #pragma unroll
      for (int ks = 0; ks < 2; ++ks) {
        s16x8 kf = *(const s16x8*)&Ks[cur][ni * 16 + lc][ks * 32 + lg * 8];
        c[ni] = __builtin_amdgcn_mfma_f32_16x16x32_bf16(kf, aq[ks], c[ni], 0, 0, 0);
      }
    }
    #pragma unroll
    for (int ni = 0; ni < 4; ++ni) {
      float4 p4;
      #pragma unroll
      for (int r = 0; r < 4; ++r) {
        int col = kt * 64 + ni * 16 + lg * 4 + r;
        bool ok = (col <= qrow) && mk[col] && qv;
        float p = ok ? exp2f(fmaf(c[ni][r], K1, bf2f(btab[qrow - col])) - C) : 0.f;
        (&p4.x)[r] = p;
        QPs[wave * 16 + lc][ni * 16 + lg * 4 + r] = f2bf(p);
      }
      *(float4*)&aout[(size_t)qrow * 2048 + kt * 64 + ni * 16 + lg * 4] = p4;
    }
    // PV: QPs strip is wave-local (written and read by same wave's rows)
    #pragma unroll
    for (int ks = 0; ks < 2; ++ks) {
      s16x8 pa = *(const s16x8*)&QPs[wave * 16 + lc][ks * 32 + lg * 8];
      #pragma unroll
      for (int ni = 0; ni < 4; ++ni) {
        s16x8 vfr = *(const s16x8*)&VTs[cur][ni * 16 + lc][ks * 32 + lg * 8];
        yacc[ni] = __builtin_amdgcn_mfma_f32_16x16x32_bf16(pa, vfr, yacc[ni], 0, 0, 0);
      }
    }
    if (kt < qt) {
      *(s16x8*)&Ks[cur ^ 1][sr][sc]       = kn0;
      *(s16x8*)&Ks[cur ^ 1][sr + 32][sc]  = kn1;
      *(s16x8*)&VTs[cur ^ 1][sr][sc]      = vn0;
      *(s16x8*)&VTs[cur ^ 1][sr + 32][sc] = vn1;
    }
    __syncthreads();
  }

  // zero upper triangle (attn bytes written exactly once per row)
  int zc0 = (qt + 1) * 64;
  if (zc0 < 2048) {
    float4 z4 = {0.f, 0.f, 0.f, 0.f};
    for (int rr = 0; rr < 64; ++rr) {
      float* dst = aout + (size_t)(qt * 64 + rr) * 2048;
      for (int cc = zc0 + (tid << 2); cc < 2048; cc += 1024)
        *(float4*)&dst[cc] = z4;
    }
  }

  // y store (padded-query rows: all p were 0 -> yacc 0)
  #pragma unroll
  for (int ni = 0; ni < 4; ++ni) {
    int col = h * 64 + ni * 16 + lc;
    #pragma unroll
    for (int r = 0; r < 4; ++r) {
      size_t row = rowbase + wave * 16 + lg * 4 + r;
      y_ws[row * 1024 + col] = f2bf(yacc[ni][r]);
    }
  }
}

// ---------------------------------------------------------------------------
extern "C" void kernel_launch(void* const* d_in, const int* in_sizes, int n_in,
                              void* d_out, int out_size, void* d_ws, size_t ws_size,
                              hipStream_t stream)
{
  const float* x         = (const float*)d_in[0];
  const int*   mask      = (const int*)d_in[1];
  const float* W_qkv     = (const float*)d_in[4];
  const float* W_out     = (const float*)d_in[5];
  const float* rel_table = (const float*)d_in[6];

  char* ws = (char*)d_ws;
  short*  xb     = (short*)(ws);                 //  8,388,608 B (reused as vt)
  short*  WqkvT  = (short*)(ws + 8388608);       //  6,291,456 B (reused as ml)
  short*  WoutT  = (short*)(ws + 14680064);      //  2,097,152 B
  short*  tabS   = (short*)(ws + 16777216);      //     65,536 B
  short*  qkv    = (short*)(ws + 16908288);      // 25,165,824 B
  short*  y_ws   = (short*)(ws + 42074112);      //  8,388,608 B
  short*  vt     = xb;                           // V^T, written after gemm1 reads xb
  float2* ml     = (float2*)WqkvT;               // written after gemm1 reads WqkvT

  float* y_out    = (float*)d_out;
  float* attn_out = y_out + (size_t)2 * 2048 * 1024;

  cast_f32_bf16<<<2048, 256, 0, stream>>>(x, xb, 4194304);
  transpose_cast<<<dim3(3072 / 32, 1024 / 32), dim3(32, 8), 0, stream>>>(W_qkv, WqkvT, 1024, 3072);
  transpose_cast<<<dim3(1024 / 32, 1024 / 32), dim3(32, 8), 0, stream>>>(W_out, WoutT, 1024, 1024);
  transpose_table_k<<<128, 256, 0, stream>>>(rel_table, tabS);

  gemm_bt<false><<<dim3(24, 32), 256, 0, stream>>>(xb, WqkvT, (void*)qkv, 4096, 3072, 1024);

  vt_transpose<<<dim3(64, 32, 2), dim3(32, 8), 0, stream>>>(qkv, vt);

  attn_stats<<<1024, 256, 0, stream>>>(qkv, mask, tabS, ml);
  attn_emit<<<1024, 256, 0, stream>>>(qkv, vt, mask, tabS, ml, attn_out, y_ws);

  gemm_bt<true><<<dim3(8, 32), 256, 0, stream>>>(y_ws, WoutT, (void*)y_out, 4096, 1024, 1024);
}

// Round 4
// 304.670 us; speedup vs baseline: 1.1105x; 1.1105x over previous
//
#include <hip/hip_runtime.h>
#include <hip/hip_bf16.h>

// ---------------------------------------------------------------------------
// Problem: N=2, S=2048, C=1024, A=1024, H=16, d=64, MAXLEN=2048
// Outputs: y [2,2048,1024] fp32  then  attn [2,16,2048,2048] fp32 (concat flat)
// ---------------------------------------------------------------------------

typedef __attribute__((ext_vector_type(8))) short s16x8;   // 8 x bf16 bits (4 VGPR)
typedef __attribute__((ext_vector_type(4))) float f32x4;   // MFMA acc

#define NEGV (-1e30f)
#define K1   0.1803368801111244f   /* 0.125 * log2(e) */

static __device__ __forceinline__ short f2bf(float f) {
  unsigned u = __float_as_uint(f);
  unsigned r = (u + 0x7fffu + ((u >> 16) & 1u)) >> 16;
  return (short)r;
}
static __device__ __forceinline__ float bf2f(short s) {
  return __uint_as_float(((unsigned)(unsigned short)s) << 16);
}

// async global->LDS, 16B per lane; lds dest must be wave-uniform (HW adds lane*16)
static __device__ __forceinline__ void gload_lds16(const void* g, void* l) {
  __builtin_amdgcn_global_load_lds(
      (const __attribute__((address_space(1))) void*)g,
      (__attribute__((address_space(3))) void*)l, 16, 0, 0);
}

// barrier that does NOT drain vmcnt: global stores stay in flight.
// staging here is reg->ds_write, so lgkmcnt(0) is sufficient for LDS visibility.
static __device__ __forceinline__ void block_sync_lds() {
  __builtin_amdgcn_sched_barrier(0);
  asm volatile("s_waitcnt lgkmcnt(0)" ::: "memory");
  __builtin_amdgcn_s_barrier();
  __builtin_amdgcn_sched_barrier(0);
}

// ---------------- elementwise cast fp32 -> bf16 ----------------------------
__global__ void cast_f32_bf16(const float* __restrict__ in, short* __restrict__ out, int n) {
  int i = (blockIdx.x * 256 + threadIdx.x) * 8;
  if (i >= n) return;
  float4 a = *(const float4*)&in[i];
  float4 b = *(const float4*)&in[i + 4];
  s16x8 v;
  v[0] = f2bf(a.x); v[1] = f2bf(a.y); v[2] = f2bf(a.z); v[3] = f2bf(a.w);
  v[4] = f2bf(b.x); v[5] = f2bf(b.y); v[6] = f2bf(b.z); v[7] = f2bf(b.w);
  *(s16x8*)&out[i] = v;
}

// ---------------- transpose + cast: [R][Cc] fp32 -> [Cc][R] bf16 -----------
__global__ void transpose_cast(const float* __restrict__ in, short* __restrict__ out,
                               int R, int Cc) {
  __shared__ float tile[32][33];
  int c0 = blockIdx.x * 32, r0 = blockIdx.y * 32;
  int tx = threadIdx.x, ty = threadIdx.y;          // block (32,8)
  for (int i = 0; i < 32; i += 8)
    tile[ty + i][tx] = in[(size_t)(r0 + ty + i) * Cc + c0 + tx];
  __syncthreads();
  for (int i = 0; i < 32; i += 8)
    out[(size_t)(c0 + ty + i) * R + r0 + tx] = f2bf(tile[tx][ty + i]);
}

// -------- rel_table [2048][16] fp32 -> [16][2048] bf16, scaled by log2e ----
__global__ void transpose_table_k(const float* __restrict__ in, short* __restrict__ out) {
  int i = blockIdx.x * 256 + threadIdx.x;
  if (i >= 2048 * 16) return;
  int l = i >> 4, h = i & 15;
  out[h * 2048 + l] = f2bf(in[i] * 1.4426950408889634f);
}

// ---------------- mask [2][2048] int -> 64 u64 bitwords --------------------
__global__ void mask_pack(const int* __restrict__ mask, unsigned long long* __restrict__ mkb) {
  int g = blockIdx.x * 256 + threadIdx.x;          // 0..4095
  unsigned long long b = __ballot(mask[g] != 0);
  if ((threadIdx.x & 63) == 0) mkb[g >> 6] = b;
}

// ---------------- V pre-transpose: qkv V-part -> VT[n][vcol][s] bf16 -------
__global__ void vt_transpose(const short* __restrict__ qkv, short* __restrict__ vt) {
  __shared__ short tile[32][33];
  int nn = blockIdx.z;
  int c0 = blockIdx.y * 32;                        // v-col (= h*64+dd)
  int r0 = blockIdx.x * 32;                        // s
  int tx = threadIdx.x, ty = threadIdx.y;          // block (32,8)
  for (int i = 0; i < 32; i += 8)
    tile[ty + i][tx] = qkv[(size_t)(nn * 2048 + r0 + ty + i) * 3072 + 2048 + c0 + tx];
  __syncthreads();
  for (int i = 0; i < 32; i += 8)
    vt[(size_t)(nn * 1024 + c0 + ty + i) * 2048 + r0 + tx] = tile[tx][ty + i];
}

// ---------------- bf16 MFMA GEMM (m97 structure): C = A * BT^T -------------
// 128x128 tile, BK=64, linear LDS, global_load_lds width=16, 2 barriers/step.
template<bool OUT_F32>
__global__ __launch_bounds__(256) void gemm_bt(
    const short* __restrict__ A, const short* __restrict__ BT,
    void* __restrict__ Cout, int M, int Nn, int K)
{
  __shared__ short As[128 * 64];
  __shared__ short Bs[128 * 64];
  int bn = blockIdx.x, bm = blockIdx.y;
  int tid = threadIdx.x, wave = tid >> 6, lane = tid & 63;
  int wr = wave >> 1, wc = wave & 1;
  int lc = lane & 15, lg = lane >> 4;
  f32x4 acc[4][4];
  for (int i = 0; i < 4; ++i)
    for (int j = 0; j < 4; ++j) acc[i][j] = (f32x4){0.f, 0.f, 0.f, 0.f};
  const short* Abase = A  + (size_t)(bm * 128) * K;
  const short* Bbase = BT + (size_t)(bn * 128) * K;
  int srow = lane >> 3;                // 0..7 within 8-row chunk
  int scol = (lane & 7) * 8;           // element col (16B granule)
  for (int k0 = 0; k0 < K; k0 += 64) {
    __syncthreads();                   // prev frag reads done before overwrite
    #pragma unroll
    for (int it = 0; it < 4; ++it) {
      int chunk = it * 4 + wave;       // 0..15; lds dest uniform per wave
      int grow = chunk * 8 + srow;
      gload_lds16(&Abase[(size_t)grow * K + k0 + scol], &As[chunk * 512]);
      gload_lds16(&Bbase[(size_t)grow * K + k0 + scol], &Bs[chunk * 512]);
    }
    __syncthreads();                   // drains vmcnt -> LDS valid
    #pragma unroll
    for (int ks = 0; ks < 2; ++ks) {
      s16x8 af[4], bfr[4];
      #pragma unroll
      for (int mi = 0; mi < 4; ++mi)
        af[mi] = *(const s16x8*)&As[(wr * 64 + mi * 16 + lc) * 64 + ks * 32 + lg * 8];
      #pragma unroll
      for (int ni = 0; ni < 4; ++ni)
        bfr[ni] = *(const s16x8*)&Bs[(wc * 64 + ni * 16 + lc) * 64 + ks * 32 + lg * 8];
      #pragma unroll
      for (int mi = 0; mi < 4; ++mi)
        #pragma unroll
        for (int ni = 0; ni < 4; ++ni)
          acc[mi][ni] = __builtin_amdgcn_mfma_f32_16x16x32_bf16(af[mi], bfr[ni], acc[mi][ni], 0, 0, 0);
    }
  }
  int row0 = bm * 128 + wr * 64, col0 = bn * 128 + wc * 64;
  for (int mi = 0; mi < 4; ++mi)
    for (int ni = 0; ni < 4; ++ni)
      for (int r = 0; r < 4; ++r) {
        int row = row0 + mi * 16 + lg * 4 + r;
        int col = col0 + ni * 16 + lc;
        if constexpr (OUT_F32)
          ((float*)Cout)[(size_t)row * Nn + col] = acc[mi][ni][r];
        else
          ((short*)Cout)[(size_t)row * Nn + col] = f2bf(acc[mi][ni][r]);
      }
}

// ---------------- fused attention (stats + emit in one kernel) -------------
// grid 1024 desc-qt LPT: qt = 31-(bid>>5), nh = bid&31 (bid%8=nh%8 XCD spread).
// Swapped QK^T: lane owns q-row (lc); 4 consecutive k per acc reg.
// Log2-domain softmax; mask via SGPR u64 bitwords; raw barriers (no vmcnt
// drain) so the 537MB attn stores overlap compute.
__global__ __launch_bounds__(256) void attn_fused(
    const short* __restrict__ qkv,     // [4096][3072] bf16
    const short* __restrict__ vt,      // [2][1024][2048] bf16 (V^T)
    const unsigned long long* __restrict__ mkb,  // [2][32]
    const short* __restrict__ tabS,    // [16][2048] bf16, *log2e
    float* __restrict__ attn_out,      // [2][16][2048][2048]
    short* __restrict__ y_ws)          // [4096][1024] bf16
{
  int bid = blockIdx.x;
  int qt = 31 - (bid >> 5);
  int nh = bid & 31;
  int n = nh >> 4, h = nh & 15;
  int tid = threadIdx.x, wave = tid >> 6, lane = tid & 63;
  int lc = lane & 15, lg = lane >> 4, lg4 = lg * 4;

  __shared__ short QPs[64][72];        // Q, then P (wave-local strips)
  __shared__ short Ks[2][64][72];
  __shared__ short VTs[2][64][72];
  __shared__ short btab[2048];

  for (int i = tid; i < 2048; i += 256) btab[i] = tabS[h * 2048 + i];

  int sr = tid >> 3, sc = (tid & 7) * 8;
  size_t rowbase = (size_t)(n * 2048 + qt * 64);
  const short* qbase  = qkv + rowbase * 3072 + h * 64;
  const short* kbase0 = qkv + (size_t)(n * 2048) * 3072 + 1024 + h * 64;
  const short* vtbase = vt + (size_t)(n * 1024 + h * 64) * 2048;
  const unsigned long long* mw = mkb + n * 32;

  *(s16x8*)&QPs[sr][sc]      = *(const s16x8*)&qbase[(size_t)sr * 3072 + sc];
  *(s16x8*)&QPs[sr + 32][sc] = *(const s16x8*)&qbase[(size_t)(sr + 32) * 3072 + sc];
  *(s16x8*)&Ks[0][sr][sc]      = *(const s16x8*)&kbase0[(size_t)sr * 3072 + sc];
  *(s16x8*)&Ks[0][sr + 32][sc] = *(const s16x8*)&kbase0[(size_t)(sr + 32) * 3072 + sc];
  __syncthreads();

  s16x8 aq[2];
  #pragma unroll
  for (int ks = 0; ks < 2; ++ks)
    aq[ks] = *(const s16x8*)&QPs[wave * 16 + lc][ks * 32 + lg * 8];
  int qrow = qt * 64 + wave * 16 + lc;
  bool qv = ((mw[qrow >> 6] >> (qrow & 63)) & 1ull) != 0;
  float m = NEGV, l = 0.f;

  // ---------------- pass 1: row max + sum ----------------
  for (int kt = 0; kt <= qt; ++kt) {
    int cur = kt & 1;
    s16x8 kn0, kn1;
    if (kt < qt) {
      const short* kb = kbase0 + (size_t)(kt + 1) * 64 * 3072;
      kn0 = *(const s16x8*)&kb[(size_t)sr * 3072 + sc];
      kn1 = *(const s16x8*)&kb[(size_t)(sr + 32) * 3072 + sc];
    }
    unsigned long long w = mw[kt];
    f32x4 c[4];
    __builtin_amdgcn_s_setprio(1);
    #pragma unroll
    for (int ni = 0; ni < 4; ++ni) {
      c[ni] = (f32x4){0.f, 0.f, 0.f, 0.f};
      #pragma unroll
      for (int ks = 0; ks < 2; ++ks) {
        s16x8 kf = *(const s16x8*)&Ks[cur][ni * 16 + lc][ks * 32 + lg * 8];
        c[ni] = __builtin_amdgcn_mfma_f32_16x16x32_bf16(kf, aq[ks], c[ni], 0, 0, 0);
      }
    }
    __builtin_amdgcn_s_setprio(0);
    float vals[4][4], tmax = NEGV;
    #pragma unroll
    for (int ni = 0; ni < 4; ++ni)
      #pragma unroll
      for (int r = 0; r < 4; ++r) {
        int col = kt * 64 + ni * 16 + lg4 + r;
        float bb = bf2f(btab[qrow - col]);           // OOB-neg -> garbage, masked
        bool ok = (((w >> (col & 63)) & 1ull) != 0) && (col <= qrow);
        float v = ok ? fmaf(c[ni][r], K1, bb) : NEGV;
        vals[ni][r] = v;
        tmax = fmaxf(tmax, v);
      }
    tmax = fmaxf(tmax, __shfl_xor(tmax, 16));
    tmax = fmaxf(tmax, __shfl_xor(tmax, 32));
    float mn = fmaxf(m, tmax);
    float s = 0.f;
    #pragma unroll
    for (int ni = 0; ni < 4; ++ni)
      #pragma unroll
      for (int r = 0; r < 4; ++r)
        s += exp2f(vals[ni][r] - mn);
    s += __shfl_xor(s, 16);
    s += __shfl_xor(s, 32);
    l = l * exp2f(m - mn) + s;
    m = mn;
    if (kt < qt) {
      *(s16x8*)&Ks[cur ^ 1][sr][sc]      = kn0;
      *(s16x8*)&Ks[cur ^ 1][sr + 32][sc] = kn1;
    }
    block_sync_lds();
  }

  float C_ = qv ? (m + __log2f(l)) : 0.0f;   // valid rows: l>=exp2(0)>0

  f32x4 yacc[4];
  #pragma unroll
  for (int ni = 0; ni < 4; ++ni) yacc[ni] = (f32x4){0.f, 0.f, 0.f, 0.f};
  float* aout = attn_out + (size_t)(n * 16 + h) * 2048 * 2048;

  // re-stage tile 0 for pass 2 (prev barrier protects Ks[?] reads)
  *(s16x8*)&Ks[0][sr][sc]       = *(const s16x8*)&kbase0[(size_t)sr * 3072 + sc];
  *(s16x8*)&Ks[0][sr + 32][sc]  = *(const s16x8*)&kbase0[(size_t)(sr + 32) * 3072 + sc];
  *(s16x8*)&VTs[0][sr][sc]      = *(const s16x8*)&vtbase[(size_t)sr * 2048 + sc];
  *(s16x8*)&VTs[0][sr + 32][sc] = *(const s16x8*)&vtbase[(size_t)(sr + 32) * 2048 + sc];
  block_sync_lds();

  // ---------------- pass 2: normalized attn (float4) + PV ----------------
  for (int kt = 0; kt <= qt; ++kt) {
    int cur = kt & 1;
    s16x8 kn0, kn1, vn0, vn1;
    if (kt < qt) {
      const short* kb = kbase0 + (size_t)(kt + 1) * 64 * 3072;
      kn0 = *(const s16x8*)&kb[(size_t)sr * 3072 + sc];
      kn1 = *(const s16x8*)&kb[(size_t)(sr + 32) * 3072 + sc];
      vn0 = *(const s16x8*)&vtbase[(size_t)sr * 2048 + (kt + 1) * 64 + sc];
      vn1 = *(const s16x8*)&vtbase[(size_t)(sr + 32) * 2048 + (kt + 1) * 64 + sc];
    }
    unsigned long long w = mw[kt];
    f32x4 c[4];
    __builtin_amdgcn_s_setprio(1);
    #pragma unroll
    for (int ni = 0; ni < 4; ++ni) {
      c[ni] = (f32x4){0.f, 0.f, 0.f, 0.f};
      #pragma unroll
      for (int ks = 0; ks < 2; ++ks) {
        s16x8 kf = *(const s16x8*)&Ks[cur][ni * 16 + lc][ks * 32 + lg * 8];
        c[ni] = __builtin_amdgcn_mfma_f32_16x16x32_bf16(kf, aq[ks], c[ni], 0, 0, 0);
      }
    }
    __builtin_amdgcn_s_setprio(0);
    #pragma unroll
    for (int ni = 0; ni < 4; ++ni) {
      float4 p4;
      #pragma unroll
      for (int r = 0; r < 4; ++r) {
        int col = kt * 64 + ni * 16 + lg4 + r;
        float bb = bf2f(btab[qrow - col]);
        bool ok = (((w >> (col & 63)) & 1ull) != 0) && (col <= qrow) && qv;
        float v = ok ? (fmaf(c[ni][r], K1, bb) - C_) : -3.0e38f;
        (&p4.x)[r] = exp2f(v);
      }
      *(float4*)&aout[(size_t)qrow * 2048 + kt * 64 + ni * 16 + lg4] = p4;
      unsigned lo = (unsigned)(unsigned short)f2bf(p4.x) | ((unsigned)(unsigned short)f2bf(p4.y) << 16);
      unsigned hi = (unsigned)(unsigned short)f2bf(p4.z) | ((unsigned)(unsigned short)f2bf(p4.w) << 16);
      uint2 pk; pk.x = lo; pk.y = hi;
      *(uint2*)&QPs[wave * 16 + lc][ni * 16 + lg4] = pk;   // wave-local strip
    }
    __builtin_amdgcn_s_setprio(1);
    #pragma unroll
    for (int ks = 0; ks < 2; ++ks) {
      s16x8 pa = *(const s16x8*)&QPs[wave * 16 + lc][ks * 32 + lg * 8];
      #pragma unroll
      for (int ni = 0; ni < 4; ++ni) {
        s16x8 vfr = *(const s16x8*)&VTs[cur][ni * 16 + lc][ks * 32 + lg * 8];
        yacc[ni] = __builtin_amdgcn_mfma_f32_16x16x32_bf16(pa, vfr, yacc[ni], 0, 0, 0);
      }
    }
    __builtin_amdgcn_s_setprio(0);
    if (kt < qt) {
      *(s16x8*)&Ks[cur ^ 1][sr][sc]       = kn0;
      *(s16x8*)&Ks[cur ^ 1][sr + 32][sc]  = kn1;
      *(s16x8*)&VTs[cur ^ 1][sr][sc]      = vn0;
      *(s16x8*)&VTs[cur ^ 1][sr + 32][sc] = vn1;
    }
    block_sync_lds();
  }

  // zero upper triangle (each attn byte written exactly once)
  int zc0 = (qt + 1) * 64;
  if (zc0 < 2048) {
    float4 z4 = {0.f, 0.f, 0.f, 0.f};
    for (int rr = 0; rr < 64; ++rr) {
      float* dst = aout + (size_t)(qt * 64 + rr) * 2048;
      for (int cc = zc0 + (tid << 2); cc < 2048; cc += 1024)
        *(float4*)&dst[cc] = z4;
    }
  }

  // y store (padded-query rows: all p forced 0 -> yacc 0)
  #pragma unroll
  for (int ni = 0; ni < 4; ++ni) {
    int col = h * 64 + ni * 16 + lc;
    #pragma unroll
    for (int r = 0; r < 4; ++r) {
      size_t row = rowbase + wave * 16 + lg * 4 + r;
      y_ws[row * 1024 + col] = f2bf(yacc[ni][r]);
    }
  }
}

// ---------------------------------------------------------------------------
extern "C" void kernel_launch(void* const* d_in, const int* in_sizes, int n_in,
                              void* d_out, int out_size, void* d_ws, size_t ws_size,
                              hipStream_t stream)
{
  const float* x         = (const float*)d_in[0];
  const int*   mask      = (const int*)d_in[1];
  const float* W_qkv     = (const float*)d_in[4];
  const float* W_out     = (const float*)d_in[5];
  const float* rel_table = (const float*)d_in[6];

  char* ws = (char*)d_ws;
  short*  xb     = (short*)(ws);                 //  8,388,608 B (reused as vt)
  short*  WqkvT  = (short*)(ws + 8388608);       //  6,291,456 B
  short*  WoutT  = (short*)(ws + 14680064);      //  2,097,152 B
  short*  tabS   = (short*)(ws + 16777216);      //     65,536 B
  unsigned long long* mkb = (unsigned long long*)(ws + 16842752); // 512 B
  short*  qkv    = (short*)(ws + 16908288);      // 25,165,824 B
  short*  y_ws   = (short*)(ws + 42074112);      //  8,388,608 B
  short*  vt     = xb;                           // V^T, written after gemm1 reads xb

  float* y_out    = (float*)d_out;
  float* attn_out = y_out + (size_t)2 * 2048 * 1024;

  cast_f32_bf16<<<2048, 256, 0, stream>>>(x, xb, 4194304);
  transpose_cast<<<dim3(3072 / 32, 1024 / 32), dim3(32, 8), 0, stream>>>(W_qkv, WqkvT, 1024, 3072);
  transpose_cast<<<dim3(1024 / 32, 1024 / 32), dim3(32, 8), 0, stream>>>(W_out, WoutT, 1024, 1024);
  transpose_table_k<<<128, 256, 0, stream>>>(rel_table, tabS);
  mask_pack<<<16, 256, 0, stream>>>(mask, mkb);

  gemm_bt<false><<<dim3(24, 32), 256, 0, stream>>>(xb, WqkvT, (void*)qkv, 4096, 3072, 1024);

  vt_transpose<<<dim3(64, 32, 2), dim3(32, 8), 0, stream>>>(qkv, vt);

  attn_fused<<<1024, 256, 0, stream>>>(qkv, vt, mkb, tabS, attn_out, y_ws);

  gemm_bt<true><<<dim3(8, 32), 256, 0, stream>>>(y_ws, WoutT, (void*)y_out, 4096, 1024, 1024);
}